// Round 3
// baseline (618.778 us; speedup 1.0000x reference)
//
#include <hip/hip_runtime.h>
#include <hip/hip_bf16.h>

#define N_FACTS 100000
#define TM 32

typedef __attribute__((ext_vector_type(8))) short bf16x8;
typedef __attribute__((ext_vector_type(4))) float f32x4;

__device__ __forceinline__ short bfs(float x) {
    union { __hip_bfloat16 h; short s; } u;
    u.h = __float2bfloat16(x);
    return u.s;
}

__device__ __forceinline__ bf16x8 cvt8(const float4 a, const float4 b) {
    bf16x8 r;
    r[0] = bfs(a.x); r[1] = bfs(a.y); r[2] = bfs(a.z); r[3] = bfs(a.w);
    r[4] = bfs(b.x); r[5] = bfs(b.y); r[6] = bfs(b.z); r[7] = bfs(b.w);
    return r;
}

__device__ __forceinline__ float mish_f(float v) {
    // mish(x) = x * tanh(softplus(x)) = x * (t^2 + 2t) / (t^2 + 2t + 2), t = e^x
    float t = expf(v);
    float p = t * (t + 2.0f);
    float r = v * (p / (p + 2.0f));
    return (v > 20.0f) ? v : r;
}

template<int D, int A>
__global__ __launch_bounds__(256)
void msg_kernel(const float* __restrict__ emb,            // [N_NODES*64] f32
                const int* __restrict__ idx,              // [G, F*A] int32
                const float* __restrict__ wi,             // [G, D, D] f32
                const float* __restrict__ bi,             // [G, D] f32
                const float* __restrict__ wo,             // [G, D, D] f32
                const float* __restrict__ bo,             // [G, D] f32
                float* __restrict__ out_msgs,             // f32, group base applied
                float* __restrict__ out_idx)              // f32, group base applied
{
    constexpr int DPX = D + 8;       // bf16 rows, +16B pad
    constexpr int DPO = D + 4;       // f32 rows, +16B pad
    constexpr int CT = D / 64;       // 16-col MFMA tiles per wave
    constexpr int RC = D / 8;        // bf16x8 chunks per row
    __shared__ __hip_bfloat16 Xs[TM][DPX];
    __shared__ union UU { __hip_bfloat16 h[TM][DPX]; float o[TM][DPO]; } U;

    const int g   = blockIdx.y;
    const int f0  = blockIdx.x * TM;
    const int tid = threadIdx.x;
    const int lane = tid & 63;
    const int w    = tid >> 6;
    const long gFA = (long)g * N_FACTS * A;

    // ---- gather X rows into LDS (f32 -> bf16), and emit indices output (f32) ----
    {
        const int* idx_g = idx + gFA + (long)f0 * A;
        for (int c = tid; c < TM * RC; c += 256) {
            int r = c / RC;
            int i = (c - r * RC) * 8;
            int node = idx_g[r * A + (i >> 6)];
            const float4* src = (const float4*)(emb + (long)node * 64 + (i & 63));
            *(bf16x8*)(&Xs[r][i]) = cvt8(src[0], src[1]);
        }
        if (tid < TM * A) {
            int node = idx_g[tid];
            out_idx[gFA + (long)f0 * A + tid] = (float)node;
        }
    }
    __syncthreads();

    const int ar   = lane & 15;   // A-row / B-col within 16-tile
    const int kg   = lane >> 4;   // k-group (8 elems each)
    const int col0 = w * (D / 4); // this wave's output column base

    const float* wi_g = wi + (long)g * D * D;
    const float* wo_g = wo + (long)g * D * D;

    // ---- GEMM1: acc = X @ Wi^T ----
    f32x4 acc[2][CT];
    #pragma unroll
    for (int rt = 0; rt < 2; rt++)
        #pragma unroll
        for (int ct = 0; ct < CT; ct++) acc[rt][ct] = (f32x4)0.0f;

    #pragma unroll
    for (int kk = 0; kk < D; kk += 32) {
        bf16x8 a0 = *(const bf16x8*)(&Xs[ar][kk + kg * 8]);
        bf16x8 a1 = *(const bf16x8*)(&Xs[16 + ar][kk + kg * 8]);
        #pragma unroll
        for (int ct = 0; ct < CT; ct++) {
            const float4* bp = (const float4*)(wi_g + (long)(col0 + ct * 16 + ar) * D + kk + kg * 8);
            bf16x8 b = cvt8(bp[0], bp[1]);
            acc[0][ct] = __builtin_amdgcn_mfma_f32_16x16x32_bf16(a0, b, acc[0][ct], 0, 0, 0);
            acc[1][ct] = __builtin_amdgcn_mfma_f32_16x16x32_bf16(a1, b, acc[1][ct], 0, 0, 0);
        }
    }

    // ---- epilogue 1: bias + mish -> U.h ----
    #pragma unroll
    for (int ct = 0; ct < CT; ct++) {
        const int col = col0 + ct * 16 + ar;
        const float bias = bi[g * D + col];
        #pragma unroll
        for (int rt = 0; rt < 2; rt++)
            #pragma unroll
            for (int j = 0; j < 4; j++) {
                float v = acc[rt][ct][j] + bias;
                U.h[rt * 16 + kg * 4 + j][col] = __float2bfloat16(mish_f(v));
            }
    }
    __syncthreads();

    // ---- GEMM2: acc = H @ Wo^T ----
    #pragma unroll
    for (int rt = 0; rt < 2; rt++)
        #pragma unroll
        for (int ct = 0; ct < CT; ct++) acc[rt][ct] = (f32x4)0.0f;

    #pragma unroll
    for (int kk = 0; kk < D; kk += 32) {
        bf16x8 a0 = *(const bf16x8*)(&U.h[ar][kk + kg * 8]);
        bf16x8 a1 = *(const bf16x8*)(&U.h[16 + ar][kk + kg * 8]);
        #pragma unroll
        for (int ct = 0; ct < CT; ct++) {
            const float4* bp = (const float4*)(wo_g + (long)(col0 + ct * 16 + ar) * D + kk + kg * 8);
            bf16x8 b = cvt8(bp[0], bp[1]);
            acc[0][ct] = __builtin_amdgcn_mfma_f32_16x16x32_bf16(a0, b, acc[0][ct], 0, 0, 0);
            acc[1][ct] = __builtin_amdgcn_mfma_f32_16x16x32_bf16(a1, b, acc[1][ct], 0, 0, 0);
        }
    }
    __syncthreads();   // all H reads done before overwriting U.o

    // ---- epilogue 2: bias + residual -> U.o (f32) ----
    #pragma unroll
    for (int ct = 0; ct < CT; ct++) {
        const int col = col0 + ct * 16 + ar;
        const float bias = bo[g * D + col];
        #pragma unroll
        for (int rt = 0; rt < 2; rt++)
            #pragma unroll
            for (int j = 0; j < 4; j++) {
                int r = rt * 16 + kg * 4 + j;
                U.o[r][col] = acc[rt][ct][j] + bias + __bfloat162float(Xs[r][col]);
            }
    }
    __syncthreads();

    // ---- coalesced f32 writeout: block's 32*D outputs are contiguous ----
    {
        float* ob = out_msgs + (gFA + (long)f0 * A) * 64;
        for (int c = tid; c < TM * (D / 4); c += 256) {
            int r = c / (D / 4);
            int i = (c - r * (D / 4)) * 4;
            *(float4*)(ob + (long)r * D + i) = *(const float4*)(&U.o[r][i]);
        }
    }
}

extern "C" void kernel_launch(void* const* d_in, const int* in_sizes, int n_in,
                              void* d_out, int out_size, void* d_ws, size_t ws_size,
                              hipStream_t stream) {
    const float* emb_f = (const float*)d_in[0];
    const int*   idx_a[4] = {(const int*)d_in[1], (const int*)d_in[6],
                             (const int*)d_in[11], (const int*)d_in[16]};
    const float* wi_f[4]  = {(const float*)d_in[2], (const float*)d_in[7],
                             (const float*)d_in[12], (const float*)d_in[17]};
    const float* bi_f[4]  = {(const float*)d_in[3], (const float*)d_in[8],
                             (const float*)d_in[13], (const float*)d_in[18]};
    const float* wo_f[4]  = {(const float*)d_in[4], (const float*)d_in[9],
                             (const float*)d_in[14], (const float*)d_in[19]};
    const float* bo_f[4]  = {(const float*)d_in[5], (const float*)d_in[10],
                             (const float*)d_in[15], (const float*)d_in[20]};

    float* out = (float*)d_out;
    const long MSG_ELEMS = 115200000L;               // 1.8M rows * 64 (f32 elements)
    const long rowOff[4] = {0, 200000, 800000, 1400000};

    msg_kernel<64, 1><<<dim3(N_FACTS / TM, 2), 256, 0, stream>>>(
        emb_f, idx_a[0], wi_f[0], bi_f[0], wo_f[0], bo_f[0],
        out + rowOff[0] * 64, out + MSG_ELEMS + rowOff[0]);
    msg_kernel<128, 2><<<dim3(N_FACTS / TM, 3), 256, 0, stream>>>(
        emb_f, idx_a[1], wi_f[1], bi_f[1], wo_f[1], bo_f[1],
        out + rowOff[1] * 64, out + MSG_ELEMS + rowOff[1]);
    msg_kernel<192, 3><<<dim3(N_FACTS / TM, 2), 256, 0, stream>>>(
        emb_f, idx_a[2], wi_f[2], bi_f[2], wo_f[2], bo_f[2],
        out + rowOff[2] * 64, out + MSG_ELEMS + rowOff[2]);
    msg_kernel<256, 4><<<dim3(N_FACTS / TM, 1), 256, 0, stream>>>(
        emb_f, idx_a[3], wi_f[3], bi_f[3], wo_f[3], bo_f[3],
        out + rowOff[3] * 64, out + MSG_ELEMS + rowOff[3]);
}

// Round 4
// 443.362 us; speedup vs baseline: 1.3956x; 1.3956x over previous
//
#include <hip/hip_runtime.h>
#include <hip/hip_bf16.h>

#define N_FACTS 100000
#define TM 64

typedef __attribute__((ext_vector_type(8))) short bf16x8;
typedef __attribute__((ext_vector_type(4))) float f32x4;

__device__ __forceinline__ short bfs(float x) {
    union { __hip_bfloat16 h; short s; } u;
    u.h = __float2bfloat16(x);
    return u.s;
}

__device__ __forceinline__ bf16x8 cvt8(const float4 a, const float4 b) {
    bf16x8 r;
    r[0] = bfs(a.x); r[1] = bfs(a.y); r[2] = bfs(a.z); r[3] = bfs(a.w);
    r[4] = bfs(b.x); r[5] = bfs(b.y); r[6] = bfs(b.z); r[7] = bfs(b.w);
    return r;
}

__device__ __forceinline__ float mish_f(float v) {
    // mish(x) = x * (t^2 + 2t) / (t^2 + 2t + 2), t = e^x; exact saturation for v>20
    float t = expf(v);
    float p = t * (t + 2.0f);
    float r = v * (p / (p + 2.0f));
    return (v > 20.0f) ? v : r;
}

// ---- fp32 -> bf16 pre-conversion kernels ----
__global__ __launch_bounds__(256)
void cvt_emb(const float* __restrict__ in, __hip_bfloat16* __restrict__ out) {
    long e = ((long)blockIdx.x * 256 + threadIdx.x) * 8;
    const float4* s = (const float4*)(in + e);
    *(bf16x8*)(out + e) = cvt8(s[0], s[1]);
}

struct CvtW {
    const float* src[8];
    long pre[9];   // prefix sums of element counts
};

__global__ __launch_bounds__(256)
void cvt_w(CvtW a, __hip_bfloat16* __restrict__ dst) {
    long e = ((long)blockIdx.x * 256 + threadIdx.x) * 8;
    if (e >= a.pre[8]) return;
    int k = 0;
    #pragma unroll
    for (int j = 0; j < 8; j++) if (e >= a.pre[j + 1]) k = j + 1;
    const float4* s = (const float4*)(a.src[k] + (e - a.pre[k]));
    *(bf16x8*)(dst + e) = cvt8(s[0], s[1]);
}

// ---- main fused kernel: gather -> GEMM1 -> mish -> GEMM2 -> residual -> store ----
template<int D, int A, bool PRE>
__global__ __launch_bounds__(256)
void msg_kernel(const void* __restrict__ embv,            // bf16 (PRE) or f32
                const int* __restrict__ idx,              // [G, F*A]
                const void* __restrict__ wiv,             // [G, D, D] bf16 (PRE) or f32
                const float* __restrict__ bi,             // [G, D]
                const void* __restrict__ wov,             // [G, D, D]
                const float* __restrict__ bo,             // [G, D]
                float* __restrict__ out_msgs,             // f32, group base applied
                float* __restrict__ out_idx)              // f32, group base applied
{
    constexpr int DPX = D + 8;       // row stride ≡ 4 dwords (mod 32): conflict-optimal ds_read_b128
    constexpr int CT = D / 64;       // 16-col MFMA tiles per wave
    constexpr int RC = D / 8;        // bf16x8 chunks per row
    constexpr int RT = TM / 16;      // 16-row MFMA tiles
    __shared__ __hip_bfloat16 Xs[TM][DPX];
    __shared__ __hip_bfloat16 Hs[TM][DPX];

    const int g   = blockIdx.y;
    const int f0  = blockIdx.x * TM;
    const int tid = threadIdx.x;
    const int lane = tid & 63;
    const int w    = tid >> 6;
    const long gFA = (long)g * N_FACTS * A;
    const int valid = min(TM, N_FACTS - f0);

    // ---- gather X rows into LDS (bf16), emit indices output (f32) ----
    {
        const int* idx_g = idx + gFA + (long)f0 * A;
        for (int c = tid; c < TM * RC; c += 256) {
            int r = c / RC;
            int i = (c - r * RC) * 8;
            bf16x8 v = (bf16x8)0;
            if (r < valid) {
                int node = idx_g[r * A + (i >> 6)];
                if constexpr (PRE) {
                    v = *(const bf16x8*)((const __hip_bfloat16*)embv + (long)node * 64 + (i & 63));
                } else {
                    const float4* s = (const float4*)((const float*)embv + (long)node * 64 + (i & 63));
                    v = cvt8(s[0], s[1]);
                }
            }
            *(bf16x8*)(&Xs[r][i]) = v;
        }
        if (tid < valid * A) out_idx[gFA + (long)f0 * A + tid] = (float)idx_g[tid];
    }
    __syncthreads();

    const int ar   = lane & 15;   // A-row / B-col within 16-tile
    const int kg   = lane >> 4;   // k-group (8 elems each)
    const int col0 = w * (D / 4); // this wave's output column base

    f32x4 acc[RT][CT];

    // ---- GEMM1: acc = X @ Wi^T ----
    #pragma unroll
    for (int rt = 0; rt < RT; rt++)
        #pragma unroll
        for (int ct = 0; ct < CT; ct++) acc[rt][ct] = (f32x4)0.0f;

    #pragma unroll
    for (int kk = 0; kk < D; kk += 32) {
        bf16x8 a[RT];
        #pragma unroll
        for (int rt = 0; rt < RT; rt++) a[rt] = *(const bf16x8*)(&Xs[rt * 16 + ar][kk + kg * 8]);
        #pragma unroll
        for (int ct = 0; ct < CT; ct++) {
            bf16x8 b;
            const long wofs = (long)g * D * D + (long)(col0 + ct * 16 + ar) * D + kk + kg * 8;
            if constexpr (PRE) {
                b = *(const bf16x8*)((const __hip_bfloat16*)wiv + wofs);
            } else {
                const float4* bp = (const float4*)((const float*)wiv + wofs);
                b = cvt8(bp[0], bp[1]);
            }
            #pragma unroll
            for (int rt = 0; rt < RT; rt++)
                acc[rt][ct] = __builtin_amdgcn_mfma_f32_16x16x32_bf16(a[rt], b, acc[rt][ct], 0, 0, 0);
        }
    }

    // ---- epilogue 1: bias + mish -> Hs ----
    #pragma unroll
    for (int ct = 0; ct < CT; ct++) {
        const int col = col0 + ct * 16 + ar;
        const float bias = bi[g * D + col];
        #pragma unroll
        for (int rt = 0; rt < RT; rt++)
            #pragma unroll
            for (int j = 0; j < 4; j++) {
                float v = acc[rt][ct][j] + bias;
                Hs[rt * 16 + kg * 4 + j][col] = __float2bfloat16(mish_f(v));
            }
    }
    __syncthreads();

    // ---- GEMM2: acc = H @ Wo^T ----
    #pragma unroll
    for (int rt = 0; rt < RT; rt++)
        #pragma unroll
        for (int ct = 0; ct < CT; ct++) acc[rt][ct] = (f32x4)0.0f;

    #pragma unroll
    for (int kk = 0; kk < D; kk += 32) {
        bf16x8 a[RT];
        #pragma unroll
        for (int rt = 0; rt < RT; rt++) a[rt] = *(const bf16x8*)(&Hs[rt * 16 + ar][kk + kg * 8]);
        #pragma unroll
        for (int ct = 0; ct < CT; ct++) {
            bf16x8 b;
            const long wofs = (long)g * D * D + (long)(col0 + ct * 16 + ar) * D + kk + kg * 8;
            if constexpr (PRE) {
                b = *(const bf16x8*)((const __hip_bfloat16*)wov + wofs);
            } else {
                const float4* bp = (const float4*)((const float*)wov + wofs);
                b = cvt8(bp[0], bp[1]);
            }
            #pragma unroll
            for (int rt = 0; rt < RT; rt++)
                acc[rt][ct] = __builtin_amdgcn_mfma_f32_16x16x32_bf16(a[rt], b, acc[rt][ct], 0, 0, 0);
        }
    }

    // ---- epilogue 2: bias + residual, direct f32 stores (64B coalesced segments) ----
    {
        float* ob = out_msgs + (gFA + (long)f0 * A) * 64;
        #pragma unroll
        for (int ct = 0; ct < CT; ct++) {
            const int col = col0 + ct * 16 + ar;
            const float bias = bo[g * D + col];
            #pragma unroll
            for (int rt = 0; rt < RT; rt++)
                #pragma unroll
                for (int j = 0; j < 4; j++) {
                    int r = rt * 16 + kg * 4 + j;
                    if (r < valid)
                        ob[(long)r * D + col] = acc[rt][ct][j] + bias + __bfloat162float(Xs[r][col]);
                }
        }
    }
}

extern "C" void kernel_launch(void* const* d_in, const int* in_sizes, int n_in,
                              void* d_out, int out_size, void* d_ws, size_t ws_size,
                              hipStream_t stream) {
    const float* emb_f = (const float*)d_in[0];
    const int*   idx_a[4] = {(const int*)d_in[1], (const int*)d_in[6],
                             (const int*)d_in[11], (const int*)d_in[16]};
    const float* wi_f[4]  = {(const float*)d_in[2], (const float*)d_in[7],
                             (const float*)d_in[12], (const float*)d_in[17]};
    const float* bi_f[4]  = {(const float*)d_in[3], (const float*)d_in[8],
                             (const float*)d_in[13], (const float*)d_in[18]};
    const float* wo_f[4]  = {(const float*)d_in[4], (const float*)d_in[9],
                             (const float*)d_in[14], (const float*)d_in[19]};
    const float* bo_f[4]  = {(const float*)d_in[5], (const float*)d_in[10],
                             (const float*)d_in[15], (const float*)d_in[20]};
    const int Gs[4] = {2, 3, 2, 1};
    const int Ds[4] = {64, 128, 192, 256};

    float* out = (float*)d_out;
    const long MSG_ELEMS = 115200000L;               // 1.8M rows * 64 (f32)
    const long rowOff[4] = {0, 200000, 800000, 1400000};
    const int GX = (N_FACTS + TM - 1) / TM;          // 1563

    const long EMB_ELEMS = 6400000L;                 // 100000*64
    long wElems[8], wPre[9];
    wPre[0] = 0;
    for (int k = 0; k < 4; k++) {
        wElems[2 * k]     = (long)Gs[k] * Ds[k] * Ds[k];
        wElems[2 * k + 1] = wElems[2 * k];
    }
    for (int j = 0; j < 8; j++) wPre[j + 1] = wPre[j] + wElems[j];
    const long NEED = (EMB_ELEMS + wPre[8]) * 2;

    if (ws_size >= (size_t)NEED) {
        __hip_bfloat16* emb_b = (__hip_bfloat16*)d_ws;
        __hip_bfloat16* w_b   = emb_b + EMB_ELEMS;

        cvt_emb<<<dim3(EMB_ELEMS / 8 / 256), dim3(256), 0, stream>>>(emb_f, emb_b);
        CvtW cw;
        for (int k = 0; k < 4; k++) { cw.src[2 * k] = wi_f[k]; cw.src[2 * k + 1] = wo_f[k]; }
        for (int j = 0; j < 9; j++) cw.pre[j] = wPre[j];
        cvt_w<<<dim3((wPre[8] / 8 + 255) / 256), dim3(256), 0, stream>>>(cw, w_b);

        const __hip_bfloat16* wi_b[4], *wo_b[4];
        for (int k = 0; k < 4; k++) { wi_b[k] = w_b + wPre[2 * k]; wo_b[k] = w_b + wPre[2 * k + 1]; }

        msg_kernel<64, 1, true><<<dim3(GX, 2), 256, 0, stream>>>(
            emb_b, idx_a[0], wi_b[0], bi_f[0], wo_b[0], bo_f[0],
            out + rowOff[0] * 64, out + MSG_ELEMS + rowOff[0]);
        msg_kernel<128, 2, true><<<dim3(GX, 3), 256, 0, stream>>>(
            emb_b, idx_a[1], wi_b[1], bi_f[1], wo_b[1], bo_f[1],
            out + rowOff[1] * 64, out + MSG_ELEMS + rowOff[1]);
        msg_kernel<192, 3, true><<<dim3(GX, 2), 256, 0, stream>>>(
            emb_b, idx_a[2], wi_b[2], bi_f[2], wo_b[2], bo_f[2],
            out + rowOff[2] * 64, out + MSG_ELEMS + rowOff[2]);
        msg_kernel<256, 4, true><<<dim3(GX, 1), 256, 0, stream>>>(
            emb_b, idx_a[3], wi_b[3], bi_f[3], wo_b[3], bo_f[3],
            out + rowOff[3] * 64, out + MSG_ELEMS + rowOff[3]);
    } else {
        msg_kernel<64, 1, false><<<dim3(GX, 2), 256, 0, stream>>>(
            emb_f, idx_a[0], wi_f[0], bi_f[0], wo_f[0], bo_f[0],
            out + rowOff[0] * 64, out + MSG_ELEMS + rowOff[0]);
        msg_kernel<128, 2, false><<<dim3(GX, 3), 256, 0, stream>>>(
            emb_f, idx_a[1], wi_f[1], bi_f[1], wo_f[1], bo_f[1],
            out + rowOff[1] * 64, out + MSG_ELEMS + rowOff[1]);
        msg_kernel<192, 3, false><<<dim3(GX, 2), 256, 0, stream>>>(
            emb_f, idx_a[2], wi_f[2], bi_f[2], wo_f[2], bo_f[2],
            out + rowOff[2] * 64, out + MSG_ELEMS + rowOff[2]);
        msg_kernel<256, 4, false><<<dim3(GX, 1), 256, 0, stream>>>(
            emb_f, idx_a[3], wi_f[3], bi_f[3], wo_f[3], bo_f[3],
            out + rowOff[3] * 64, out + MSG_ELEMS + rowOff[3]);
    }
}

// Round 5
// 360.598 us; speedup vs baseline: 1.7160x; 1.2295x over previous
//
#include <hip/hip_runtime.h>
#include <hip/hip_bf16.h>

#define N_FACTS 100000
#define TM 64

typedef __attribute__((ext_vector_type(8))) short bf16x8;
typedef __attribute__((ext_vector_type(4))) short bf16x4;
typedef __attribute__((ext_vector_type(4))) float f32x4;

__device__ __forceinline__ short bfs(float x) {
    union { __hip_bfloat16 h; short s; } u;
    u.h = __float2bfloat16(x);
    return u.s;
}

__device__ __forceinline__ float b2f(short s) {
    union { float f; unsigned u; } u;
    u.u = ((unsigned)(unsigned short)s) << 16;
    return u.f;
}

__device__ __forceinline__ bf16x8 cvt8(const float4 a, const float4 b) {
    bf16x8 r;
    r[0] = bfs(a.x); r[1] = bfs(a.y); r[2] = bfs(a.z); r[3] = bfs(a.w);
    r[4] = bfs(b.x); r[5] = bfs(b.y); r[6] = bfs(b.z); r[7] = bfs(b.w);
    return r;
}

__device__ __forceinline__ float mish_f(float v) {
    // mish(x) = x * (t^2+2t)/(t^2+2t+2), t=e^x; exact passthrough for v>20
    float t = __expf(v);
    float p = t * (t + 2.0f);
    float r = v * p * __builtin_amdgcn_rcpf(p + 2.0f);
    return (v > 20.0f) ? v : r;
}

// ---- fp32 -> bf16 pre-conversion kernels ----
__global__ __launch_bounds__(256)
void cvt_emb(const float* __restrict__ in, __hip_bfloat16* __restrict__ out) {
    long e = ((long)blockIdx.x * 256 + threadIdx.x) * 8;
    const float4* s = (const float4*)(in + e);
    *(bf16x8*)(out + e) = cvt8(s[0], s[1]);
}

struct CvtW {
    const float* src[8];
    long pre[9];   // prefix sums of element counts
};

__global__ __launch_bounds__(256)
void cvt_w(CvtW a, __hip_bfloat16* __restrict__ dst) {
    long e = ((long)blockIdx.x * 256 + threadIdx.x) * 8;
    if (e >= a.pre[8]) return;
    int k = 0;
    #pragma unroll
    for (int j = 0; j < 8; j++) if (e >= a.pre[j + 1]) k = j + 1;
    const float4* s = (const float4*)(a.src[k] + (e - a.pre[k]));
    *(bf16x8*)(dst + e) = cvt8(s[0], s[1]);
}

// ---- fused kernel: gather -> GEMM1 -> mish -> GEMM2 -> residual -> store ----
// MFMA operand order is SWAPPED (A=weights, B=facts): C/D col=lane&15 -> fact row,
// C/D row=(lane>>4)*4+j -> 4 CONSECUTIVE output columns per lane -> vector epilogues.
template<int D, int A, bool PRE>
__global__ __launch_bounds__(256)
void msg_kernel(const void* __restrict__ embv,            // bf16 (PRE) or f32
                const int* __restrict__ idx,              // [G, F*A]
                const void* __restrict__ wiv,             // [G, D, D]
                const float* __restrict__ bi,             // [G, D]
                const void* __restrict__ wov,             // [G, D, D]
                const float* __restrict__ bo,             // [G, D]
                float* __restrict__ out_msgs,             // f32, group base applied
                float* __restrict__ out_idx)              // f32, group base applied
{
    constexpr int DPX = D + 8;       // row stride ≡ 4 dwords mod 32 -> 2-way (free) LDS aliasing
    constexpr int CT = D / 64;       // 16-wide output-col tiles per wave
    constexpr int RC = D / 8;        // bf16x8 chunks per row
    constexpr int RT = TM / 16;      // 16-row fact tiles
    __shared__ __hip_bfloat16 Xs[TM][DPX];
    __shared__ __hip_bfloat16 Hs[TM][DPX];

    const int g   = blockIdx.y;
    const int f0  = blockIdx.x * TM;
    const int tid = threadIdx.x;
    const int lane = tid & 63;
    const int w    = tid >> 6;
    const long gFA = (long)g * N_FACTS * A;
    const int valid = min(TM, N_FACTS - f0);

    // ---- gather X rows into LDS (bf16), emit indices output (f32) ----
    {
        const int* idx_g = idx + gFA + (long)f0 * A;
        for (int c = tid; c < TM * RC; c += 256) {
            int r = c / RC;
            int i = (c - r * RC) * 8;
            bf16x8 v = (bf16x8)0;
            if (r < valid) {
                int node = idx_g[r * A + (i >> 6)];
                if constexpr (PRE) {
                    v = *(const bf16x8*)((const __hip_bfloat16*)embv + (long)node * 64 + (i & 63));
                } else {
                    const float4* s = (const float4*)((const float*)embv + (long)node * 64 + (i & 63));
                    v = cvt8(s[0], s[1]);
                }
            }
            *(bf16x8*)(&Xs[r][i]) = v;
        }
        if (tid < valid * A) out_idx[gFA + (long)f0 * A + tid] = (float)idx_g[tid];
    }
    __syncthreads();

    const int ar = lane & 15;    // fact-in-tile (B col / D col); W row for A-frag
    const int kg = lane >> 4;    // k-group for A/B frags; 4-col group for C/D
    const int c0 = w * (D / 4);  // this wave's output-column base

    f32x4 acc[RT][CT];

    // ---- GEMM1: acc = Wi x X^T  (out[fact][col] via swapped lanes) ----
    #pragma unroll
    for (int rt = 0; rt < RT; rt++)
        #pragma unroll
        for (int ct = 0; ct < CT; ct++) acc[rt][ct] = (f32x4)0.0f;

    #pragma unroll
    for (int kk = 0; kk < D; kk += 32) {
        bf16x8 xb[RT];
        #pragma unroll
        for (int rt = 0; rt < RT; rt++) xb[rt] = *(const bf16x8*)(&Xs[rt * 16 + ar][kk + kg * 8]);
        #pragma unroll
        for (int ct = 0; ct < CT; ct++) {
            bf16x8 wf;
            const long wofs = (long)g * D * D + (long)(c0 + ct * 16 + ar) * D + kk + kg * 8;
            if constexpr (PRE) {
                wf = *(const bf16x8*)((const __hip_bfloat16*)wiv + wofs);
            } else {
                const float4* bp = (const float4*)((const float*)wiv + wofs);
                wf = cvt8(bp[0], bp[1]);
            }
            #pragma unroll
            for (int rt = 0; rt < RT; rt++)
                acc[rt][ct] = __builtin_amdgcn_mfma_f32_16x16x32_bf16(wf, xb[rt], acc[rt][ct], 0, 0, 0);
        }
    }

    // ---- epilogue 1: bias + mish -> Hs (vector ds_write_b64 per tile) ----
    #pragma unroll
    for (int ct = 0; ct < CT; ct++) {
        const int cb = c0 + ct * 16 + kg * 4;       // 4 consecutive cols per lane
        const float4 bi4 = *(const float4*)(bi + g * D + cb);
        #pragma unroll
        for (int rt = 0; rt < RT; rt++) {
            bf16x4 hv;
            hv[0] = bfs(mish_f(acc[rt][ct][0] + bi4.x));
            hv[1] = bfs(mish_f(acc[rt][ct][1] + bi4.y));
            hv[2] = bfs(mish_f(acc[rt][ct][2] + bi4.z));
            hv[3] = bfs(mish_f(acc[rt][ct][3] + bi4.w));
            *(bf16x4*)(&Hs[rt * 16 + ar][cb]) = hv;
        }
    }
    __syncthreads();

    // ---- GEMM2: acc = Wo x H^T ----
    #pragma unroll
    for (int rt = 0; rt < RT; rt++)
        #pragma unroll
        for (int ct = 0; ct < CT; ct++) acc[rt][ct] = (f32x4)0.0f;

    #pragma unroll
    for (int kk = 0; kk < D; kk += 32) {
        bf16x8 hb[RT];
        #pragma unroll
        for (int rt = 0; rt < RT; rt++) hb[rt] = *(const bf16x8*)(&Hs[rt * 16 + ar][kk + kg * 8]);
        #pragma unroll
        for (int ct = 0; ct < CT; ct++) {
            bf16x8 wf;
            const long wofs = (long)g * D * D + (long)(c0 + ct * 16 + ar) * D + kk + kg * 8;
            if constexpr (PRE) {
                wf = *(const bf16x8*)((const __hip_bfloat16*)wov + wofs);
            } else {
                const float4* bp = (const float4*)((const float*)wov + wofs);
                wf = cvt8(bp[0], bp[1]);
            }
            #pragma unroll
            for (int rt = 0; rt < RT; rt++)
                acc[rt][ct] = __builtin_amdgcn_mfma_f32_16x16x32_bf16(wf, hb[rt], acc[rt][ct], 0, 0, 0);
        }
    }

    // ---- epilogue 2: bias + residual, float4 coalesced stores ----
    {
        float* ob = out_msgs + (gFA + (long)f0 * A) * 64;
        #pragma unroll
        for (int ct = 0; ct < CT; ct++) {
            const int cb = c0 + ct * 16 + kg * 4;
            const float4 bo4 = *(const float4*)(bo + g * D + cb);
            #pragma unroll
            for (int rt = 0; rt < RT; rt++) {
                const int r = rt * 16 + ar;
                bf16x4 xv = *(const bf16x4*)(&Xs[r][cb]);
                float4 o;
                o.x = acc[rt][ct][0] + bo4.x + b2f(xv[0]);
                o.y = acc[rt][ct][1] + bo4.y + b2f(xv[1]);
                o.z = acc[rt][ct][2] + bo4.z + b2f(xv[2]);
                o.w = acc[rt][ct][3] + bo4.w + b2f(xv[3]);
                if (r < valid) *(float4*)(ob + (long)r * D + cb) = o;
            }
        }
    }
}

extern "C" void kernel_launch(void* const* d_in, const int* in_sizes, int n_in,
                              void* d_out, int out_size, void* d_ws, size_t ws_size,
                              hipStream_t stream) {
    const float* emb_f = (const float*)d_in[0];
    const int*   idx_a[4] = {(const int*)d_in[1], (const int*)d_in[6],
                             (const int*)d_in[11], (const int*)d_in[16]};
    const float* wi_f[4]  = {(const float*)d_in[2], (const float*)d_in[7],
                             (const float*)d_in[12], (const float*)d_in[17]};
    const float* bi_f[4]  = {(const float*)d_in[3], (const float*)d_in[8],
                             (const float*)d_in[13], (const float*)d_in[18]};
    const float* wo_f[4]  = {(const float*)d_in[4], (const float*)d_in[9],
                             (const float*)d_in[14], (const float*)d_in[19]};
    const float* bo_f[4]  = {(const float*)d_in[5], (const float*)d_in[10],
                             (const float*)d_in[15], (const float*)d_in[20]};
    const int Gs[4] = {2, 3, 2, 1};
    const int Ds[4] = {64, 128, 192, 256};

    float* out = (float*)d_out;
    const long MSG_ELEMS = 115200000L;               // 1.8M rows * 64 (f32)
    const long rowOff[4] = {0, 200000, 800000, 1400000};
    const int GX = (N_FACTS + TM - 1) / TM;          // 1563

    const long EMB_ELEMS = 6400000L;                 // 100000*64
    long wElems[8], wPre[9];
    wPre[0] = 0;
    for (int k = 0; k < 4; k++) {
        wElems[2 * k]     = (long)Gs[k] * Ds[k] * Ds[k];
        wElems[2 * k + 1] = wElems[2 * k];
    }
    for (int j = 0; j < 8; j++) wPre[j + 1] = wPre[j] + wElems[j];
    const long NEED = (EMB_ELEMS + wPre[8]) * 2;

    if (ws_size >= (size_t)NEED) {
        __hip_bfloat16* emb_b = (__hip_bfloat16*)d_ws;
        __hip_bfloat16* w_b   = emb_b + EMB_ELEMS;

        cvt_emb<<<dim3(EMB_ELEMS / 8 / 256), dim3(256), 0, stream>>>(emb_f, emb_b);
        CvtW cw;
        for (int k = 0; k < 4; k++) { cw.src[2 * k] = wi_f[k]; cw.src[2 * k + 1] = wo_f[k]; }
        for (int j = 0; j < 9; j++) cw.pre[j] = wPre[j];
        cvt_w<<<dim3((wPre[8] / 8 + 255) / 256), dim3(256), 0, stream>>>(cw, w_b);

        const __hip_bfloat16* wi_b[4], *wo_b[4];
        for (int k = 0; k < 4; k++) { wi_b[k] = w_b + wPre[2 * k]; wo_b[k] = w_b + wPre[2 * k + 1]; }

        msg_kernel<64, 1, true><<<dim3(GX, 2), 256, 0, stream>>>(
            emb_b, idx_a[0], wi_b[0], bi_f[0], wo_b[0], bo_f[0],
            out + rowOff[0] * 64, out + MSG_ELEMS + rowOff[0]);
        msg_kernel<128, 2, true><<<dim3(GX, 3), 256, 0, stream>>>(
            emb_b, idx_a[1], wi_b[1], bi_f[1], wo_b[1], bo_f[1],
            out + rowOff[1] * 64, out + MSG_ELEMS + rowOff[1]);
        msg_kernel<192, 3, true><<<dim3(GX, 2), 256, 0, stream>>>(
            emb_b, idx_a[2], wi_b[2], bi_f[2], wo_b[2], bo_f[2],
            out + rowOff[2] * 64, out + MSG_ELEMS + rowOff[2]);
        msg_kernel<256, 4, true><<<dim3(GX, 1), 256, 0, stream>>>(
            emb_b, idx_a[3], wi_b[3], bi_f[3], wo_b[3], bo_f[3],
            out + rowOff[3] * 64, out + MSG_ELEMS + rowOff[3]);
    } else {
        msg_kernel<64, 1, false><<<dim3(GX, 2), 256, 0, stream>>>(
            emb_f, idx_a[0], wi_f[0], bi_f[0], wo_f[0], bo_f[0],
            out + rowOff[0] * 64, out + MSG_ELEMS + rowOff[0]);
        msg_kernel<128, 2, false><<<dim3(GX, 3), 256, 0, stream>>>(
            emb_f, idx_a[1], wi_f[1], bi_f[1], wo_f[1], bo_f[1],
            out + rowOff[1] * 64, out + MSG_ELEMS + rowOff[1]);
        msg_kernel<192, 3, false><<<dim3(GX, 2), 256, 0, stream>>>(
            emb_f, idx_a[2], wi_f[2], bi_f[2], wo_f[2], bo_f[2],
            out + rowOff[2] * 64, out + MSG_ELEMS + rowOff[2]);
        msg_kernel<256, 4, false><<<dim3(GX, 1), 256, 0, stream>>>(
            emb_f, idx_a[3], wi_f[3], bi_f[3], wo_f[3], bo_f[3],
            out + rowOff[3] * 64, out + MSG_ELEMS + rowOff[3]);
    }
}